// Round 5
// baseline (41.152 us; speedup 1.0000x reference)
//
#include <hip/hip_runtime.h>
#include <hip/hip_cooperative_groups.h>
#include <math.h>

namespace cg = cooperative_groups;

#define N_RAYS    4096
#define N_SAMPLES 192
#define WSZ       160
#define EQU_H     768
#define EQU_W     1536
#define RGB_DIM   12
#define WIDTH     128
#define NEAR_T    0.05f
#define FAR_T     3.0f
#define INTERVAL  0.5f
#define FAST_THRES 1e-4f
// log(1/(1-1e-4) - 1)
#define ACT_SHIFT (-9.210240366975849f)
// alpha(d) > 1e-4  <=>  d > 0.693057...; conservative margin
#define DENS_CUTOFF 0.69214f

#define NVOX (WSZ * WSZ * WSZ)
#define NV4  (NVOX / 4)            /* 1,024,000 float4s */
#define GRID_B 256                 /* blocks; <=256 -> 1/CU co-residency guaranteed */
#define SLICE (NV4 / GRID_B)       /* 4000 float4 per block */
#define RAYS_PER_BLOCK (N_RAYS / GRID_B)   /* 16 */

// ---------------- helpers ----------------
__device__ __forceinline__ float trilinear_density(const float* __restrict__ g,
                                                   float px, float py, float pz) {
    float ix = fminf(fmaxf((px + 1.f) * 0.5f * (WSZ - 1), 0.f), (float)(WSZ - 1));
    float iy = fminf(fmaxf((py + 1.f) * 0.5f * (WSZ - 1), 0.f), (float)(WSZ - 1));
    float iz = fminf(fmaxf((pz + 1.f) * 0.5f * (WSZ - 1), 0.f), (float)(WSZ - 1));
    int x0 = (int)floorf(ix); int x1 = min(x0 + 1, WSZ - 1); float wx = ix - (float)x0;
    int y0 = (int)floorf(iy); int y1 = min(y0 + 1, WSZ - 1); float wy = iy - (float)y0;
    int z0 = (int)floorf(iz); int z1 = min(z0 + 1, WSZ - 1); float wz = iz - (float)z0;
    const int HW = WSZ * WSZ;
    const float* p00 = g + z0 * HW + y0 * WSZ;
    const float* p01 = g + z0 * HW + y1 * WSZ;
    const float* p10 = g + z1 * HW + y0 * WSZ;
    const float* p11 = g + z1 * HW + y1 * WSZ;
    float c00 = p00[x0] * (1.f - wx) + p00[x1] * wx;
    float c01 = p01[x0] * (1.f - wx) + p01[x1] * wx;
    float c10 = p10[x0] * (1.f - wx) + p10[x1] * wx;
    float c11 = p11[x0] * (1.f - wx) + p11[x1] * wx;
    float c0 = c00 * (1.f - wy) + c01 * wy;
    float c1 = c10 * (1.f - wy) + c11 * wy;
    return c0 * (1.f - wz) + c1 * wz;
}

__device__ __forceinline__ float feat_elem(int j, float cx, float cy, float cz,
                                           float dx, float dy, float dz) {
    // feat = [posenc(contracted,10) (63), posenc(dir,4) (27)], total 90
    float val;
    if (j < 63) {
        if (j < 3) {
            val = (j == 0) ? cx : ((j == 1) ? cy : cz);
        } else {
            int jj = j - 3; int f = jj / 6; int k = jj % 6;
            int axis = k % 3;
            float c = (axis == 0) ? cx : ((axis == 1) ? cy : cz);
            float xb = c * exp2f((float)f);
            val = (k < 3) ? sinf(xb) : cosf(xb);
        }
    } else {
        int j2 = j - 63;
        if (j2 < 3) {
            val = (j2 == 0) ? dx : ((j2 == 1) ? dy : dz);
        } else {
            int jj = j2 - 3; int f = jj / 6; int k = jj % 6;
            int axis = k % 3;
            float c = (axis == 0) ? dx : ((axis == 1) ? dy : dz);
            float xb = c * exp2f((float)f);
            val = (k < 3) ? sinf(xb) : cosf(xb);
        }
    }
    return val;
}

// wave-cooperative MLP for one surviving sample; returns rgb broadcast to all lanes
__device__ void wave_mlp(int lane, float cx, float cy, float cz,
                         float dx, float dy, float dz,
                         const float* __restrict__ equ,
                         const float* __restrict__ dW0, const float* __restrict__ db0,
                         const float* __restrict__ dW1, const float* __restrict__ db1,
                         const float* __restrict__ dW2, const float* __restrict__ db2,
                         const float* __restrict__ cW0, const float* __restrict__ cb0,
                         const float* __restrict__ cW1, const float* __restrict__ cb1,
                         const float* __restrict__ cW2, const float* __restrict__ cb2,
                         float& r0, float& r1, float& r2) {
    float f_lo = feat_elem(lane, cx, cy, cz, dx, dy, dz);
    float f_hi = (lane < 26) ? feat_elem(lane + 64, cx, cy, cz, dx, dy, dz) : 0.f;

    // deformation layer 0: 90 -> 128 (lane owns neurons lane, lane+64)
    float a_lo = db0[lane], a_hi = db0[lane + 64];
    for (int k = 0; k < 90; k++) {
        float fk = (k < 64) ? __shfl(f_lo, k) : __shfl(f_hi, k - 64);
        a_lo += fk * dW0[k * WIDTH + lane];
        a_hi += fk * dW0[k * WIDTH + 64 + lane];
    }
    float h_lo = fmaxf(a_lo, 0.f), h_hi = fmaxf(a_hi, 0.f);

    // deformation layer 1: 128 -> 128
    a_lo = db1[lane]; a_hi = db1[lane + 64];
    for (int k = 0; k < 128; k++) {
        float hk = (k < 64) ? __shfl(h_lo, k) : __shfl(h_hi, k - 64);
        a_lo += hk * dW1[k * WIDTH + lane];
        a_hi += hk * dW1[k * WIDTH + 64 + lane];
    }
    float g_lo = fmaxf(a_lo, 0.f), g_hi = fmaxf(a_hi, 0.f);

    // duv: 128 -> 2 (reduce across lanes)
    float p0 = g_lo * dW2[lane * 2 + 0] + g_hi * dW2[(64 + lane) * 2 + 0];
    float p1 = g_lo * dW2[lane * 2 + 1] + g_hi * dW2[(64 + lane) * 2 + 1];
    #pragma unroll
    for (int o = 32; o > 0; o >>= 1) { p0 += __shfl_xor(p0, o); p1 += __shfl_xor(p1, o); }
    float duv0 = db2[0] + p0, duv1 = db2[1] + p1;

    // base uv + offset, clip
    float rc = sqrtf(cx * cx + cy * cy + cz * cz) + 1e-9f;
    float u = atan2f(cx, cz) * 0.3183098861837907f;
    float v = asinf(fminf(fmaxf(cy / rc, -1.f), 1.f)) * 0.6366197723675814f;
    float uu = fminf(fmaxf(u + duv0, -1.f), 1.f);
    float vv = fminf(fmaxf(v + duv1, -1.f), 1.f);

    // bilinear equ sample: lane < 12 handles its channel
    float gx = fminf(fmaxf((uu + 1.f) * 0.5f * (EQU_W - 1), 0.f), (float)(EQU_W - 1));
    float gy = fminf(fmaxf((vv + 1.f) * 0.5f * (EQU_H - 1), 0.f), (float)(EQU_H - 1));
    int x0 = (int)floorf(gx); int x1 = min(x0 + 1, EQU_W - 1); float wx = gx - (float)x0;
    int y0 = (int)floorf(gy); int y1 = min(y0 + 1, EQU_H - 1); float wy = gy - (float)y0;
    float k0v = 0.f;
    if (lane < RGB_DIM) {
        const float* gch = equ + (size_t)lane * EQU_H * EQU_W;
        float c0 = gch[y0 * EQU_W + x0] * (1.f - wx) + gch[y0 * EQU_W + x1] * wx;
        float c1 = gch[y1 * EQU_W + x0] * (1.f - wx) + gch[y1 * EQU_W + x1] * wx;
        k0v = c0 * (1.f - wy) + c1 * wy;
    }

    // color layer 0: 12 -> 128
    a_lo = cb0[lane]; a_hi = cb0[lane + 64];
    for (int k = 0; k < RGB_DIM; k++) {
        float kk = __shfl(k0v, k);
        a_lo += kk * cW0[k * WIDTH + lane];
        a_hi += kk * cW0[k * WIDTH + 64 + lane];
    }
    h_lo = fmaxf(a_lo, 0.f); h_hi = fmaxf(a_hi, 0.f);

    // color layer 1: 128 -> 128
    a_lo = cb1[lane]; a_hi = cb1[lane + 64];
    for (int k = 0; k < 128; k++) {
        float hk = (k < 64) ? __shfl(h_lo, k) : __shfl(h_hi, k - 64);
        a_lo += hk * cW1[k * WIDTH + lane];
        a_hi += hk * cW1[k * WIDTH + 64 + lane];
    }
    g_lo = fmaxf(a_lo, 0.f); g_hi = fmaxf(a_hi, 0.f);

    // rgb: 128 -> 3 (reduce), sigmoid
    float q0 = g_lo * cW2[lane * 3 + 0] + g_hi * cW2[(64 + lane) * 3 + 0];
    float q1 = g_lo * cW2[lane * 3 + 1] + g_hi * cW2[(64 + lane) * 3 + 1];
    float q2 = g_lo * cW2[lane * 3 + 2] + g_hi * cW2[(64 + lane) * 3 + 2];
    #pragma unroll
    for (int o = 32; o > 0; o >>= 1) {
        q0 += __shfl_xor(q0, o); q1 += __shfl_xor(q1, o); q2 += __shfl_xor(q2, o);
    }
    r0 = 1.f / (1.f + expf(-(cb2[0] + q0)));
    r1 = 1.f / (1.f + expf(-(cb2[1] + q1)));
    r2 = 1.f / (1.f + expf(-(cb2[2] + q2)));
}

// full per-ray render (slow path), wave-cooperative; exact reference semantics
__device__ void render_ray(int lane, int r,
        const float* __restrict__ rays_o, const float* __restrict__ rays_d,
        const float* __restrict__ dgrid, const float* __restrict__ equ,
        const float* __restrict__ dW0, const float* __restrict__ db0,
        const float* __restrict__ dW1, const float* __restrict__ db1,
        const float* __restrict__ dW2, const float* __restrict__ db2,
        const float* __restrict__ cW0, const float* __restrict__ cb0,
        const float* __restrict__ cW1, const float* __restrict__ cb1,
        const float* __restrict__ cW2, const float* __restrict__ cb2,
        float* __restrict__ out)
{
    float ox = rays_o[r * 3 + 0], oy = rays_o[r * 3 + 1], oz = rays_o[r * 3 + 2];
    float dx = rays_d[r * 3 + 0], dy = rays_d[r * 3 + 1], dz = rays_d[r * 3 + 2];
    float nrm = sqrtf(dx * dx + dy * dy + dz * dz) + 1e-9f;
    dx /= nrm; dy /= nrm; dz /= nrm;

    float alpha[3], cxa[3], cya[3], cza[3];
    #pragma unroll
    for (int c = 0; c < 3; c++) {
        int s = c * 64 + lane;
        float t = NEAR_T + (FAR_T - NEAR_T) * ((float)s / (float)(N_SAMPLES - 1));
        float px = ox + t * dx, py = oy + t * dy, pz = oz + t * dz;
        float rr = sqrtf(px * px + py * py + pz * pz);
        float scale = (rr <= 1.f) ? 0.5f : 0.5f * (2.f - 1.f / rr) / rr;
        cxa[c] = px * scale; cya[c] = py * scale; cza[c] = pz * scale;
        float dens = trilinear_density(dgrid, cxa[c], cya[c], cza[c]);
        float xs = dens + ACT_SHIFT;
        float sp = (xs > 20.f) ? xs : log1pf(expf(xs));
        float a = -expm1f(-sp * INTERVAL);
        alpha[c] = (a > FAST_THRES) ? a : 0.f;
    }

    // exclusive prefix product of (1 - alpha + 1e-10)
    float T[3]; float carry = 1.f;
    #pragma unroll
    for (int c = 0; c < 3; c++) {
        float inc = 1.f - alpha[c] + 1e-10f;
        #pragma unroll
        for (int o = 1; o < 64; o <<= 1) {
            float v = __shfl_up(inc, o);
            if (lane >= o) inc *= v;
        }
        float excl = __shfl_up(inc, 1);
        if (lane == 0) excl = 1.f;
        T[c] = carry * excl;
        carry *= __shfl(inc, 63);
    }

    float w[3]; float accp = 0.f;
    #pragma unroll
    for (int c = 0; c < 3; c++) {
        float ww = alpha[c] * T[c];
        w[c] = (ww > FAST_THRES) ? ww : 0.f;
        accp += w[c];
    }
    #pragma unroll
    for (int o = 32; o > 0; o >>= 1) accp += __shfl_xor(accp, o);

    float outR = 1.f - accp, outG = 1.f - accp, outB = 1.f - accp;

    #pragma unroll
    for (int c = 0; c < 3; c++) {
        unsigned long long ball = __ballot(w[c] > 0.f);
        while (ball) {
            int src = __ffsll(ball) - 1;
            ball &= ball - 1;
            float sw  = __shfl(w[c], src);
            float scx = __shfl(cxa[c], src);
            float scy = __shfl(cya[c], src);
            float scz = __shfl(cza[c], src);
            float r0, r1, r2;
            wave_mlp(lane, scx, scy, scz, dx, dy, dz, equ,
                     dW0, db0, dW1, db1, dW2, db2,
                     cW0, cb0, cW1, cb1, cW2, cb2, r0, r1, r2);
            outR += sw * r0; outG += sw * r1; outB += sw * r2;
        }
    }

    if (lane < 3) {
        float val = (lane == 0) ? outR : ((lane == 1) ? outG : outB);
        out[r * 3 + lane] = val;
    }
}

// ---------------- single cooperative kernel ----------------
__global__ __launch_bounds__(256) void k_all(
        const float* __restrict__ rays_o, const float* __restrict__ rays_d,
        const float* __restrict__ dgrid, const float* __restrict__ equ,
        const float* __restrict__ dW0, const float* __restrict__ db0,
        const float* __restrict__ dW1, const float* __restrict__ db1,
        const float* __restrict__ dW2, const float* __restrict__ db2,
        const float* __restrict__ cW0, const float* __restrict__ cb0,
        const float* __restrict__ cW1, const float* __restrict__ cb1,
        const float* __restrict__ cW2, const float* __restrict__ cb2,
        float* __restrict__ blockmax, float* __restrict__ out)
{
    const int b    = blockIdx.x;
    const int t    = threadIdx.x;
    const int lane = t & 63;
    const int wid  = t >> 6;

    // ---- phase 1: coalesced max over this block's grid slice (64 KB) ----
    const float4* g4 = (const float4*)dgrid;
    float m = -1e30f;
    const int base = b * SLICE;
    for (int i = t; i < SLICE; i += 256) {
        float4 v = g4[base + i];
        m = fmaxf(fmaxf(fmaxf(m, v.x), v.y), fmaxf(v.z, v.w));
    }
    #pragma unroll
    for (int o = 32; o > 0; o >>= 1) m = fmaxf(m, __shfl_xor(m, o));
    __shared__ float sm[4];
    if (lane == 0) sm[wid] = m;
    __syncthreads();
    if (t == 0)
        blockmax[b] = fmaxf(fmaxf(sm[0], sm[1]), fmaxf(sm[2], sm[3]));

    // ---- grid-wide sync (includes device memory fence) ----
    cg::this_grid().sync();

    // ---- phase 2: global max from the 256 slots (L2-hit), uniform branch ----
    float gmax = fmaxf(fmaxf(blockmax[lane], blockmax[lane + 64]),
                       fmaxf(blockmax[lane + 128], blockmax[lane + 192]));
    #pragma unroll
    for (int o = 32; o > 0; o >>= 1) gmax = fmaxf(gmax, __shfl_xor(gmax, o));

    if (gmax < DENS_CUTOFF) {
        // all alphas prune -> all weights 0 -> white background everywhere
        if (t < RAYS_PER_BLOCK * 3) out[b * RAYS_PER_BLOCK * 3 + t] = 1.0f;
        return;
    }

    // ---- slow path (fully general): 4 rays per wave, sequential ----
    #pragma unroll 1
    for (int q = 0; q < RAYS_PER_BLOCK / 4; q++) {
        int r = b * RAYS_PER_BLOCK + wid * (RAYS_PER_BLOCK / 4) + q;
        render_ray(lane, r, rays_o, rays_d, dgrid, equ,
                   dW0, db0, dW1, db1, dW2, db2,
                   cW0, cb0, cW1, cb1, cW2, cb2, out);
    }
}

extern "C" void kernel_launch(void* const* d_in, const int* in_sizes, int n_in,
                              void* d_out, int out_size, void* d_ws, size_t ws_size,
                              hipStream_t stream) {
    const float* rays_o = (const float*)d_in[0];
    const float* rays_d = (const float*)d_in[1];
    const float* dgrid  = (const float*)d_in[2];
    const float* equ    = (const float*)d_in[3];
    const float* dW0 = (const float*)d_in[4];
    const float* db0 = (const float*)d_in[5];
    const float* dW1 = (const float*)d_in[6];
    const float* db1 = (const float*)d_in[7];
    const float* dW2 = (const float*)d_in[8];
    const float* db2 = (const float*)d_in[9];
    const float* cW0 = (const float*)d_in[10];
    const float* cb0 = (const float*)d_in[11];
    const float* cW1 = (const float*)d_in[12];
    const float* cb1 = (const float*)d_in[13];
    const float* cW2 = (const float*)d_in[14];
    const float* cb2 = (const float*)d_in[15];
    float* out = (float*)d_out;
    float* blockmax = (float*)d_ws;   // GRID_B floats, written unconditionally every call

    void* args[] = {
        (void*)&rays_o, (void*)&rays_d, (void*)&dgrid, (void*)&equ,
        (void*)&dW0, (void*)&db0, (void*)&dW1, (void*)&db1,
        (void*)&dW2, (void*)&db2, (void*)&cW0, (void*)&cb0,
        (void*)&cW1, (void*)&cb1, (void*)&cW2, (void*)&cb2,
        (void*)&blockmax, (void*)&out
    };
    hipLaunchCooperativeKernel((const void*)k_all, dim3(GRID_B), dim3(256),
                               args, 0, stream);
}

// Round 6
// 20.230 us; speedup vs baseline: 2.0342x; 2.0342x over previous
//
#include <hip/hip_runtime.h>
#include <math.h>

#define N_RAYS    4096
#define N_SAMPLES 192
#define WSZ       160
#define EQU_H     768
#define EQU_W     1536
#define RGB_DIM   12
#define WIDTH     128
#define NEAR_T    0.05f
#define FAR_T     3.0f
#define INTERVAL  0.5f
#define FAST_THRES 1e-4f
// log(1/(1-1e-4) - 1)
#define ACT_SHIFT (-9.210240366975849f)
// alpha(d) > 1e-4  <=>  d > 0.693147...; conservative margin
#define DENS_CUTOFF 0.69214f

#define NVOX (WSZ * WSZ * WSZ)
#define NV4  (NVOX / 4)          /* 1,024,000 float4s */
#define KMAX_BLOCKS 1024
#define KMAX_STRIDE (KMAX_BLOCKS * 256)   /* 262,144 */
// reachable voxel ball: center 79.5^3, radius 79.5 + sqrt(3) < 81.25
#define BALL_R2 6601.5625f

// monotone float -> uint key: a<b (float) <=> key(a)<key(b) (uint)
__device__ __forceinline__ unsigned int fkey(float f) {
    unsigned int u = __float_as_uint(f);
    return (u & 0x80000000u) ? ~u : (u | 0x80000000u);
}

// ---------------- kernel 1: grid max -> single gate slot (atomicMax) ----------------
__global__ __launch_bounds__(256) void k_max(const float4* __restrict__ g4,
                                             unsigned int* __restrict__ gate) {
    const int tid = blockIdx.x * 256 + threadIdx.x;
    float m = -1e30f;
    #pragma unroll
    for (int u = 0; u < 4; u++) {
        int i = tid + u * KMAX_STRIDE;
        if (i < NV4) {
            // float4 i covers voxels z=i/6400, y=(i%6400)/40, x in [4*(i%40)..+3]
            int z  = i / 6400;
            int rm = i - z * 6400;
            int y  = rm / 40;
            int x4 = rm - y * 40;
            float dz = (float)z - 79.5f;
            float dy = (float)y - 79.5f;
            float dx = fmaxf(fabsf((float)(4 * x4) + 1.5f - 79.5f) - 1.5f, 0.f);
            if (dz * dz + dy * dy + dx * dx <= BALL_R2) {
                float4 v = g4[i];
                m = fmaxf(fmaxf(fmaxf(m, v.x), v.y), fmaxf(v.z, v.w));
            }
        }
    }
    #pragma unroll
    for (int o = 32; o > 0; o >>= 1) m = fmaxf(m, __shfl_xor(m, o));
    __shared__ float sm[4];
    if ((threadIdx.x & 63) == 0) sm[threadIdx.x >> 6] = m;
    __syncthreads();
    if (threadIdx.x == 0) {
        float bm = fmaxf(fmaxf(sm[0], sm[1]), fmaxf(sm[2], sm[3]));
        // direction-safe vs any stale/poison content: result >= real max key,
        // so fast path is only taken when provably valid. Idempotent across replays.
        atomicMax(gate, fkey(bm));
    }
}

// ---------------- helpers ----------------
__device__ __forceinline__ float trilinear_density(const float* __restrict__ g,
                                                   float px, float py, float pz) {
    float ix = fminf(fmaxf((px + 1.f) * 0.5f * (WSZ - 1), 0.f), (float)(WSZ - 1));
    float iy = fminf(fmaxf((py + 1.f) * 0.5f * (WSZ - 1), 0.f), (float)(WSZ - 1));
    float iz = fminf(fmaxf((pz + 1.f) * 0.5f * (WSZ - 1), 0.f), (float)(WSZ - 1));
    int x0 = (int)floorf(ix); int x1 = min(x0 + 1, WSZ - 1); float wx = ix - (float)x0;
    int y0 = (int)floorf(iy); int y1 = min(y0 + 1, WSZ - 1); float wy = iy - (float)y0;
    int z0 = (int)floorf(iz); int z1 = min(z0 + 1, WSZ - 1); float wz = iz - (float)z0;
    const int HW = WSZ * WSZ;
    const float* p00 = g + z0 * HW + y0 * WSZ;
    const float* p01 = g + z0 * HW + y1 * WSZ;
    const float* p10 = g + z1 * HW + y0 * WSZ;
    const float* p11 = g + z1 * HW + y1 * WSZ;
    float c00 = p00[x0] * (1.f - wx) + p00[x1] * wx;
    float c01 = p01[x0] * (1.f - wx) + p01[x1] * wx;
    float c10 = p10[x0] * (1.f - wx) + p10[x1] * wx;
    float c11 = p11[x0] * (1.f - wx) + p11[x1] * wx;
    float c0 = c00 * (1.f - wy) + c01 * wy;
    float c1 = c10 * (1.f - wy) + c11 * wy;
    return c0 * (1.f - wz) + c1 * wz;
}

__device__ __forceinline__ float feat_elem(int j, float cx, float cy, float cz,
                                           float dx, float dy, float dz) {
    // feat = [posenc(contracted,10) (63), posenc(dir,4) (27)], total 90
    float val;
    if (j < 63) {
        if (j < 3) {
            val = (j == 0) ? cx : ((j == 1) ? cy : cz);
        } else {
            int jj = j - 3; int f = jj / 6; int k = jj % 6;
            int axis = k % 3;
            float c = (axis == 0) ? cx : ((axis == 1) ? cy : cz);
            float xb = c * exp2f((float)f);
            val = (k < 3) ? sinf(xb) : cosf(xb);
        }
    } else {
        int j2 = j - 63;
        if (j2 < 3) {
            val = (j2 == 0) ? dx : ((j2 == 1) ? dy : dz);
        } else {
            int jj = j2 - 3; int f = jj / 6; int k = jj % 6;
            int axis = k % 3;
            float c = (axis == 0) ? dx : ((axis == 1) ? dy : dz);
            float xb = c * exp2f((float)f);
            val = (k < 3) ? sinf(xb) : cosf(xb);
        }
    }
    return val;
}

// wave-cooperative MLP for one surviving sample; returns rgb broadcast to all lanes
__device__ void wave_mlp(int lane, float cx, float cy, float cz,
                         float dx, float dy, float dz,
                         const float* __restrict__ equ,
                         const float* __restrict__ dW0, const float* __restrict__ db0,
                         const float* __restrict__ dW1, const float* __restrict__ db1,
                         const float* __restrict__ dW2, const float* __restrict__ db2,
                         const float* __restrict__ cW0, const float* __restrict__ cb0,
                         const float* __restrict__ cW1, const float* __restrict__ cb1,
                         const float* __restrict__ cW2, const float* __restrict__ cb2,
                         float& r0, float& r1, float& r2) {
    float f_lo = feat_elem(lane, cx, cy, cz, dx, dy, dz);
    float f_hi = (lane < 26) ? feat_elem(lane + 64, cx, cy, cz, dx, dy, dz) : 0.f;

    // deformation layer 0: 90 -> 128 (lane owns neurons lane, lane+64)
    float a_lo = db0[lane], a_hi = db0[lane + 64];
    for (int k = 0; k < 90; k++) {
        float fk = (k < 64) ? __shfl(f_lo, k) : __shfl(f_hi, k - 64);
        a_lo += fk * dW0[k * WIDTH + lane];
        a_hi += fk * dW0[k * WIDTH + 64 + lane];
    }
    float h_lo = fmaxf(a_lo, 0.f), h_hi = fmaxf(a_hi, 0.f);

    // deformation layer 1: 128 -> 128
    a_lo = db1[lane]; a_hi = db1[lane + 64];
    for (int k = 0; k < 128; k++) {
        float hk = (k < 64) ? __shfl(h_lo, k) : __shfl(h_hi, k - 64);
        a_lo += hk * dW1[k * WIDTH + lane];
        a_hi += hk * dW1[k * WIDTH + 64 + lane];
    }
    float g_lo = fmaxf(a_lo, 0.f), g_hi = fmaxf(a_hi, 0.f);

    // duv: 128 -> 2 (reduce across lanes)
    float p0 = g_lo * dW2[lane * 2 + 0] + g_hi * dW2[(64 + lane) * 2 + 0];
    float p1 = g_lo * dW2[lane * 2 + 1] + g_hi * dW2[(64 + lane) * 2 + 1];
    #pragma unroll
    for (int o = 32; o > 0; o >>= 1) { p0 += __shfl_xor(p0, o); p1 += __shfl_xor(p1, o); }
    float duv0 = db2[0] + p0, duv1 = db2[1] + p1;

    // base uv + offset, clip
    float rc = sqrtf(cx * cx + cy * cy + cz * cz) + 1e-9f;
    float u = atan2f(cx, cz) * 0.3183098861837907f;
    float v = asinf(fminf(fmaxf(cy / rc, -1.f), 1.f)) * 0.6366197723675814f;
    float uu = fminf(fmaxf(u + duv0, -1.f), 1.f);
    float vv = fminf(fmaxf(v + duv1, -1.f), 1.f);

    // bilinear equ sample: lane < 12 handles its channel
    float gx = fminf(fmaxf((uu + 1.f) * 0.5f * (EQU_W - 1), 0.f), (float)(EQU_W - 1));
    float gy = fminf(fmaxf((vv + 1.f) * 0.5f * (EQU_H - 1), 0.f), (float)(EQU_H - 1));
    int x0 = (int)floorf(gx); int x1 = min(x0 + 1, EQU_W - 1); float wx = gx - (float)x0;
    int y0 = (int)floorf(gy); int y1 = min(y0 + 1, EQU_H - 1); float wy = gy - (float)y0;
    float k0v = 0.f;
    if (lane < RGB_DIM) {
        const float* gch = equ + (size_t)lane * EQU_H * EQU_W;
        float c0 = gch[y0 * EQU_W + x0] * (1.f - wx) + gch[y0 * EQU_W + x1] * wx;
        float c1 = gch[y1 * EQU_W + x0] * (1.f - wx) + gch[y1 * EQU_W + x1] * wx;
        k0v = c0 * (1.f - wy) + c1 * wy;
    }

    // color layer 0: 12 -> 128
    a_lo = cb0[lane]; a_hi = cb0[lane + 64];
    for (int k = 0; k < RGB_DIM; k++) {
        float kk = __shfl(k0v, k);
        a_lo += kk * cW0[k * WIDTH + lane];
        a_hi += kk * cW0[k * WIDTH + 64 + lane];
    }
    h_lo = fmaxf(a_lo, 0.f); h_hi = fmaxf(a_hi, 0.f);

    // color layer 1: 128 -> 128
    a_lo = cb1[lane]; a_hi = cb1[lane + 64];
    for (int k = 0; k < 128; k++) {
        float hk = (k < 64) ? __shfl(h_lo, k) : __shfl(h_hi, k - 64);
        a_lo += hk * cW1[k * WIDTH + lane];
        a_hi += hk * cW1[k * WIDTH + 64 + lane];
    }
    g_lo = fmaxf(a_lo, 0.f); g_hi = fmaxf(a_hi, 0.f);

    // rgb: 128 -> 3 (reduce), sigmoid
    float q0 = g_lo * cW2[lane * 3 + 0] + g_hi * cW2[(64 + lane) * 3 + 0];
    float q1 = g_lo * cW2[lane * 3 + 1] + g_hi * cW2[(64 + lane) * 3 + 1];
    float q2 = g_lo * cW2[lane * 3 + 2] + g_hi * cW2[(64 + lane) * 3 + 2];
    #pragma unroll
    for (int o = 32; o > 0; o >>= 1) {
        q0 += __shfl_xor(q0, o); q1 += __shfl_xor(q1, o); q2 += __shfl_xor(q2, o);
    }
    r0 = 1.f / (1.f + expf(-(cb2[0] + q0)));
    r1 = 1.f / (1.f + expf(-(cb2[1] + q1)));
    r2 = 1.f / (1.f + expf(-(cb2[2] + q2)));
}

// ---------------- kernel 2: render (1 wave per ray; gate = 1 scalar) ----------------
__global__ __launch_bounds__(256) void k_render(
        const float* __restrict__ rays_o, const float* __restrict__ rays_d,
        const float* __restrict__ dgrid, const float* __restrict__ equ,
        const float* __restrict__ dW0, const float* __restrict__ db0,
        const float* __restrict__ dW1, const float* __restrict__ db1,
        const float* __restrict__ dW2, const float* __restrict__ db2,
        const float* __restrict__ cW0, const float* __restrict__ cb0,
        const float* __restrict__ cW1, const float* __restrict__ cb1,
        const float* __restrict__ cW2, const float* __restrict__ cb2,
        const unsigned int* __restrict__ gate, float* __restrict__ out)
{
    const unsigned int CUT_KEY = __float_as_uint(DENS_CUTOFF) | 0x80000000u;
    const unsigned int gk = *gate;          // uniform scalar load

    if (gk < CUT_KEY) {
        // all alphas prune -> all weights 0 -> white background everywhere.
        // 4096*3 floats = 3072 float4; blocks 0..11 write, rest retire.
        int gid = blockIdx.x * 256 + threadIdx.x;
        if (gid < (N_RAYS * 3) / 4) {
            ((float4*)out)[gid] = make_float4(1.f, 1.f, 1.f, 1.f);
        }
        return;
    }

    // ---------------- full (slow) path: always correct ----------------
    const int lane = threadIdx.x & 63;
    const int wid  = threadIdx.x >> 6;
    const int r    = blockIdx.x * 4 + wid;

    float ox = rays_o[r * 3 + 0], oy = rays_o[r * 3 + 1], oz = rays_o[r * 3 + 2];
    float dx = rays_d[r * 3 + 0], dy = rays_d[r * 3 + 1], dz = rays_d[r * 3 + 2];
    float nrm = sqrtf(dx * dx + dy * dy + dz * dz) + 1e-9f;
    dx /= nrm; dy /= nrm; dz /= nrm;

    float alpha[3], cxa[3], cya[3], cza[3];
    #pragma unroll
    for (int c = 0; c < 3; c++) {
        int s = c * 64 + lane;
        float t = NEAR_T + (FAR_T - NEAR_T) * ((float)s / (float)(N_SAMPLES - 1));
        float px = ox + t * dx, py = oy + t * dy, pz = oz + t * dz;
        float rr = sqrtf(px * px + py * py + pz * pz);
        float scale = (rr <= 1.f) ? 0.5f : 0.5f * (2.f - 1.f / rr) / rr;
        cxa[c] = px * scale; cya[c] = py * scale; cza[c] = pz * scale;
        float dens = trilinear_density(dgrid, cxa[c], cya[c], cza[c]);
        float xs = dens + ACT_SHIFT;
        float sp = (xs > 20.f) ? xs : log1pf(expf(xs));
        float a = -expm1f(-sp * INTERVAL);
        alpha[c] = (a > FAST_THRES) ? a : 0.f;
    }

    // exclusive prefix product of (1 - alpha + 1e-10)
    float T[3]; float carry = 1.f;
    #pragma unroll
    for (int c = 0; c < 3; c++) {
        float inc = 1.f - alpha[c] + 1e-10f;
        #pragma unroll
        for (int o = 1; o < 64; o <<= 1) {
            float v = __shfl_up(inc, o);
            if (lane >= o) inc *= v;
        }
        float excl = __shfl_up(inc, 1);
        if (lane == 0) excl = 1.f;
        T[c] = carry * excl;
        carry *= __shfl(inc, 63);
    }

    float w[3]; float accp = 0.f;
    #pragma unroll
    for (int c = 0; c < 3; c++) {
        float ww = alpha[c] * T[c];
        w[c] = (ww > FAST_THRES) ? ww : 0.f;
        accp += w[c];
    }
    #pragma unroll
    for (int o = 32; o > 0; o >>= 1) accp += __shfl_xor(accp, o);

    float outR = 1.f - accp, outG = 1.f - accp, outB = 1.f - accp;

    #pragma unroll
    for (int c = 0; c < 3; c++) {
        unsigned long long ball = __ballot(w[c] > 0.f);
        while (ball) {
            int src = __ffsll(ball) - 1;
            ball &= ball - 1;
            float sw  = __shfl(w[c], src);
            float scx = __shfl(cxa[c], src);
            float scy = __shfl(cya[c], src);
            float scz = __shfl(cza[c], src);
            float r0, r1, r2;
            wave_mlp(lane, scx, scy, scz, dx, dy, dz, equ,
                     dW0, db0, dW1, db1, dW2, db2,
                     cW0, cb0, cW1, cb1, cW2, cb2, r0, r1, r2);
            outR += sw * r0; outG += sw * r1; outB += sw * r2;
        }
    }

    if (lane < 3) {
        float val = (lane == 0) ? outR : ((lane == 1) ? outG : outB);
        out[r * 3 + lane] = val;
    }
}

extern "C" void kernel_launch(void* const* d_in, const int* in_sizes, int n_in,
                              void* d_out, int out_size, void* d_ws, size_t ws_size,
                              hipStream_t stream) {
    const float* rays_o = (const float*)d_in[0];
    const float* rays_d = (const float*)d_in[1];
    const float* dgrid  = (const float*)d_in[2];
    const float* equ    = (const float*)d_in[3];
    const float* dW0 = (const float*)d_in[4];
    const float* db0 = (const float*)d_in[5];
    const float* dW1 = (const float*)d_in[6];
    const float* db1 = (const float*)d_in[7];
    const float* dW2 = (const float*)d_in[8];
    const float* db2 = (const float*)d_in[9];
    const float* cW0 = (const float*)d_in[10];
    const float* cb0 = (const float*)d_in[11];
    const float* cW1 = (const float*)d_in[12];
    const float* cb1 = (const float*)d_in[13];
    const float* cW2 = (const float*)d_in[14];
    const float* cb2 = (const float*)d_in[15];
    float* out = (float*)d_out;

    unsigned int* gate = (unsigned int*)d_ws;  // single slot; atomicMax is
                                               // direction-safe vs any stale content

    k_max<<<KMAX_BLOCKS, 256, 0, stream>>>((const float4*)dgrid, gate);
    k_render<<<N_RAYS / 4, 256, 0, stream>>>(rays_o, rays_d, dgrid, equ,
                                             dW0, db0, dW1, db1, dW2, db2,
                                             cW0, cb0, cW1, cb1, cW2, cb2,
                                             gate, out);
}

// Round 7
// 12.000 us; speedup vs baseline: 3.4292x; 1.6858x over previous
//
#include <hip/hip_runtime.h>
#include <math.h>

#define N_RAYS    4096
#define N_SAMPLES 192
#define WSZ       160
#define EQU_H     768
#define EQU_W     1536
#define RGB_DIM   12
#define WIDTH     128
#define NEAR_T    0.05f
#define FAR_T     3.0f
#define INTERVAL  0.5f
#define FAST_THRES 1e-4f
// log(1/(1-1e-4) - 1)
#define ACT_SHIFT (-9.210240366975849f)
// alpha(d) > 1e-4  <=>  d > 0.693147...; conservative margin
#define DENS_CUTOFF 0.69214f

#define NVOX (WSZ * WSZ * WSZ)
#define NV4  (NVOX / 4)          /* 1,024,000 float4s */
#define KMAX_BLOCKS 1024
#define KMAX_STRIDE (KMAX_BLOCKS * 256)   /* 262,144 */
// reachable voxel ball: center 79.5^3, radius 79.5 + sqrt(3) < 81.25
#define BALL_R2 6601.5625f

// ---------------- kernel 1: per-block max over reachable voxels ----------------
// Per-block slots (NO single-address atomics: cross-XCD same-line RMWs
// serialize ~8us for 1024 blocks -- measured regression R6).
__global__ __launch_bounds__(256) void k_max(const float4* __restrict__ g4,
                                             float* __restrict__ blockmax) {
    const int tid = blockIdx.x * 256 + threadIdx.x;
    float m = -1e30f;
    #pragma unroll
    for (int u = 0; u < 4; u++) {
        int i = tid + u * KMAX_STRIDE;
        if (i < NV4) {
            // float4 i covers voxels z=i/6400, y=(i%6400)/40, x in [4*(i%40)..+3]
            int z  = i / 6400;
            int rm = i - z * 6400;
            int y  = rm / 40;
            int x4 = rm - y * 40;
            float dz = (float)z - 79.5f;
            float dy = (float)y - 79.5f;
            float dx = fmaxf(fabsf((float)(4 * x4) + 1.5f - 79.5f) - 1.5f, 0.f);
            if (dz * dz + dy * dy + dx * dx <= BALL_R2) {
                float4 v = g4[i];
                m = fmaxf(fmaxf(fmaxf(m, v.x), v.y), fmaxf(v.z, v.w));
            }
        }
    }
    #pragma unroll
    for (int o = 32; o > 0; o >>= 1) m = fmaxf(m, __shfl_xor(m, o));
    __shared__ float sm[4];
    if ((threadIdx.x & 63) == 0) sm[threadIdx.x >> 6] = m;
    __syncthreads();
    if (threadIdx.x == 0)
        blockmax[blockIdx.x] = fmaxf(fmaxf(sm[0], sm[1]), fmaxf(sm[2], sm[3]));
}

// ---------------- helpers ----------------
__device__ __forceinline__ float trilinear_density(const float* __restrict__ g,
                                                   float px, float py, float pz) {
    float ix = fminf(fmaxf((px + 1.f) * 0.5f * (WSZ - 1), 0.f), (float)(WSZ - 1));
    float iy = fminf(fmaxf((py + 1.f) * 0.5f * (WSZ - 1), 0.f), (float)(WSZ - 1));
    float iz = fminf(fmaxf((pz + 1.f) * 0.5f * (WSZ - 1), 0.f), (float)(WSZ - 1));
    int x0 = (int)floorf(ix); int x1 = min(x0 + 1, WSZ - 1); float wx = ix - (float)x0;
    int y0 = (int)floorf(iy); int y1 = min(y0 + 1, WSZ - 1); float wy = iy - (float)y0;
    int z0 = (int)floorf(iz); int z1 = min(z0 + 1, WSZ - 1); float wz = iz - (float)z0;
    const int HW = WSZ * WSZ;
    const float* p00 = g + z0 * HW + y0 * WSZ;
    const float* p01 = g + z0 * HW + y1 * WSZ;
    const float* p10 = g + z1 * HW + y0 * WSZ;
    const float* p11 = g + z1 * HW + y1 * WSZ;
    float c00 = p00[x0] * (1.f - wx) + p00[x1] * wx;
    float c01 = p01[x0] * (1.f - wx) + p01[x1] * wx;
    float c10 = p10[x0] * (1.f - wx) + p10[x1] * wx;
    float c11 = p11[x0] * (1.f - wx) + p11[x1] * wx;
    float c0 = c00 * (1.f - wy) + c01 * wy;
    float c1 = c10 * (1.f - wy) + c11 * wy;
    return c0 * (1.f - wz) + c1 * wz;
}

__device__ __forceinline__ float feat_elem(int j, float cx, float cy, float cz,
                                           float dx, float dy, float dz) {
    // feat = [posenc(contracted,10) (63), posenc(dir,4) (27)], total 90
    float val;
    if (j < 63) {
        if (j < 3) {
            val = (j == 0) ? cx : ((j == 1) ? cy : cz);
        } else {
            int jj = j - 3; int f = jj / 6; int k = jj % 6;
            int axis = k % 3;
            float c = (axis == 0) ? cx : ((axis == 1) ? cy : cz);
            float xb = c * exp2f((float)f);
            val = (k < 3) ? sinf(xb) : cosf(xb);
        }
    } else {
        int j2 = j - 63;
        if (j2 < 3) {
            val = (j2 == 0) ? dx : ((j2 == 1) ? dy : dz);
        } else {
            int jj = j2 - 3; int f = jj / 6; int k = jj % 6;
            int axis = k % 3;
            float c = (axis == 0) ? dx : ((axis == 1) ? dy : dz);
            float xb = c * exp2f((float)f);
            val = (k < 3) ? sinf(xb) : cosf(xb);
        }
    }
    return val;
}

// wave-cooperative MLP for one surviving sample; returns rgb broadcast to all lanes
__device__ void wave_mlp(int lane, float cx, float cy, float cz,
                         float dx, float dy, float dz,
                         const float* __restrict__ equ,
                         const float* __restrict__ dW0, const float* __restrict__ db0,
                         const float* __restrict__ dW1, const float* __restrict__ db1,
                         const float* __restrict__ dW2, const float* __restrict__ db2,
                         const float* __restrict__ cW0, const float* __restrict__ cb0,
                         const float* __restrict__ cW1, const float* __restrict__ cb1,
                         const float* __restrict__ cW2, const float* __restrict__ cb2,
                         float& r0, float& r1, float& r2) {
    float f_lo = feat_elem(lane, cx, cy, cz, dx, dy, dz);
    float f_hi = (lane < 26) ? feat_elem(lane + 64, cx, cy, cz, dx, dy, dz) : 0.f;

    // deformation layer 0: 90 -> 128 (lane owns neurons lane, lane+64)
    float a_lo = db0[lane], a_hi = db0[lane + 64];
    for (int k = 0; k < 90; k++) {
        float fk = (k < 64) ? __shfl(f_lo, k) : __shfl(f_hi, k - 64);
        a_lo += fk * dW0[k * WIDTH + lane];
        a_hi += fk * dW0[k * WIDTH + 64 + lane];
    }
    float h_lo = fmaxf(a_lo, 0.f), h_hi = fmaxf(a_hi, 0.f);

    // deformation layer 1: 128 -> 128
    a_lo = db1[lane]; a_hi = db1[lane + 64];
    for (int k = 0; k < 128; k++) {
        float hk = (k < 64) ? __shfl(h_lo, k) : __shfl(h_hi, k - 64);
        a_lo += hk * dW1[k * WIDTH + lane];
        a_hi += hk * dW1[k * WIDTH + 64 + lane];
    }
    float g_lo = fmaxf(a_lo, 0.f), g_hi = fmaxf(a_hi, 0.f);

    // duv: 128 -> 2 (reduce across lanes)
    float p0 = g_lo * dW2[lane * 2 + 0] + g_hi * dW2[(64 + lane) * 2 + 0];
    float p1 = g_lo * dW2[lane * 2 + 1] + g_hi * dW2[(64 + lane) * 2 + 1];
    #pragma unroll
    for (int o = 32; o > 0; o >>= 1) { p0 += __shfl_xor(p0, o); p1 += __shfl_xor(p1, o); }
    float duv0 = db2[0] + p0, duv1 = db2[1] + p1;

    // base uv + offset, clip
    float rc = sqrtf(cx * cx + cy * cy + cz * cz) + 1e-9f;
    float u = atan2f(cx, cz) * 0.3183098861837907f;
    float v = asinf(fminf(fmaxf(cy / rc, -1.f), 1.f)) * 0.6366197723675814f;
    float uu = fminf(fmaxf(u + duv0, -1.f), 1.f);
    float vv = fminf(fmaxf(v + duv1, -1.f), 1.f);

    // bilinear equ sample: lane < 12 handles its channel
    float gx = fminf(fmaxf((uu + 1.f) * 0.5f * (EQU_W - 1), 0.f), (float)(EQU_W - 1));
    float gy = fminf(fmaxf((vv + 1.f) * 0.5f * (EQU_H - 1), 0.f), (float)(EQU_H - 1));
    int x0 = (int)floorf(gx); int x1 = min(x0 + 1, EQU_W - 1); float wx = gx - (float)x0;
    int y0 = (int)floorf(gy); int y1 = min(y0 + 1, EQU_H - 1); float wy = gy - (float)y0;
    float k0v = 0.f;
    if (lane < RGB_DIM) {
        const float* gch = equ + (size_t)lane * EQU_H * EQU_W;
        float c0 = gch[y0 * EQU_W + x0] * (1.f - wx) + gch[y0 * EQU_W + x1] * wx;
        float c1 = gch[y1 * EQU_W + x0] * (1.f - wx) + gch[y1 * EQU_W + x1] * wx;
        k0v = c0 * (1.f - wy) + c1 * wy;
    }

    // color layer 0: 12 -> 128
    a_lo = cb0[lane]; a_hi = cb0[lane + 64];
    for (int k = 0; k < RGB_DIM; k++) {
        float kk = __shfl(k0v, k);
        a_lo += kk * cW0[k * WIDTH + lane];
        a_hi += kk * cW0[k * WIDTH + 64 + lane];
    }
    h_lo = fmaxf(a_lo, 0.f); h_hi = fmaxf(a_hi, 0.f);

    // color layer 1: 128 -> 128
    a_lo = cb1[lane]; a_hi = cb1[lane + 64];
    for (int k = 0; k < 128; k++) {
        float hk = (k < 64) ? __shfl(h_lo, k) : __shfl(h_hi, k - 64);
        a_lo += hk * cW1[k * WIDTH + lane];
        a_hi += hk * cW1[k * WIDTH + 64 + lane];
    }
    g_lo = fmaxf(a_lo, 0.f); g_hi = fmaxf(a_hi, 0.f);

    // rgb: 128 -> 3 (reduce), sigmoid
    float q0 = g_lo * cW2[lane * 3 + 0] + g_hi * cW2[(64 + lane) * 3 + 0];
    float q1 = g_lo * cW2[lane * 3 + 1] + g_hi * cW2[(64 + lane) * 3 + 1];
    float q2 = g_lo * cW2[lane * 3 + 2] + g_hi * cW2[(64 + lane) * 3 + 2];
    #pragma unroll
    for (int o = 32; o > 0; o >>= 1) {
        q0 += __shfl_xor(q0, o); q1 += __shfl_xor(q1, o); q2 += __shfl_xor(q2, o);
    }
    r0 = 1.f / (1.f + expf(-(cb2[0] + q0)));
    r1 = 1.f / (1.f + expf(-(cb2[1] + q1)));
    r2 = 1.f / (1.f + expf(-(cb2[2] + q2)));
}

// ---------------- kernel 2: render (1 wave per ray) ----------------
__global__ __launch_bounds__(256) void k_render(
        const float* __restrict__ rays_o, const float* __restrict__ rays_d,
        const float* __restrict__ dgrid, const float* __restrict__ equ,
        const float* __restrict__ dW0, const float* __restrict__ db0,
        const float* __restrict__ dW1, const float* __restrict__ db1,
        const float* __restrict__ dW2, const float* __restrict__ db2,
        const float* __restrict__ cW0, const float* __restrict__ cb0,
        const float* __restrict__ cW1, const float* __restrict__ cb1,
        const float* __restrict__ cW2, const float* __restrict__ cb2,
        const float* __restrict__ blockmax, float* __restrict__ out)
{
    const int lane = threadIdx.x & 63;
    const int wid  = threadIdx.x >> 6;

    // reduce the 1024 per-block max slots (L2-resident), per-wave
    float m = -1e30f;
    #pragma unroll
    for (int k = 0; k < KMAX_BLOCKS / 64; k++) m = fmaxf(m, blockmax[lane + 64 * k]);
    #pragma unroll
    for (int o = 32; o > 0; o >>= 1) m = fmaxf(m, __shfl_xor(m, o));

    if (m < DENS_CUTOFF) {
        // all alphas prune -> all weights 0 -> white background everywhere.
        // 4096*3 floats = 3072 float4: blocks 0..11 write coalesced, rest retire.
        int gid = blockIdx.x * 256 + threadIdx.x;
        if (gid < (N_RAYS * 3) / 4) {
            ((float4*)out)[gid] = make_float4(1.f, 1.f, 1.f, 1.f);
        }
        return;
    }

    // ---------------- full (slow) path: always correct ----------------
    const int r = blockIdx.x * 4 + wid;

    float ox = rays_o[r * 3 + 0], oy = rays_o[r * 3 + 1], oz = rays_o[r * 3 + 2];
    float dx = rays_d[r * 3 + 0], dy = rays_d[r * 3 + 1], dz = rays_d[r * 3 + 2];
    float nrm = sqrtf(dx * dx + dy * dy + dz * dz) + 1e-9f;
    dx /= nrm; dy /= nrm; dz /= nrm;

    float alpha[3], cxa[3], cya[3], cza[3];
    #pragma unroll
    for (int c = 0; c < 3; c++) {
        int s = c * 64 + lane;
        float t = NEAR_T + (FAR_T - NEAR_T) * ((float)s / (float)(N_SAMPLES - 1));
        float px = ox + t * dx, py = oy + t * dy, pz = oz + t * dz;
        float rr = sqrtf(px * px + py * py + pz * pz);
        float scale = (rr <= 1.f) ? 0.5f : 0.5f * (2.f - 1.f / rr) / rr;
        cxa[c] = px * scale; cya[c] = py * scale; cza[c] = pz * scale;
        float dens = trilinear_density(dgrid, cxa[c], cya[c], cza[c]);
        float xs = dens + ACT_SHIFT;
        float sp = (xs > 20.f) ? xs : log1pf(expf(xs));
        float a = -expm1f(-sp * INTERVAL);
        alpha[c] = (a > FAST_THRES) ? a : 0.f;
    }

    // exclusive prefix product of (1 - alpha + 1e-10)
    float T[3]; float carry = 1.f;
    #pragma unroll
    for (int c = 0; c < 3; c++) {
        float inc = 1.f - alpha[c] + 1e-10f;
        #pragma unroll
        for (int o = 1; o < 64; o <<= 1) {
            float v = __shfl_up(inc, o);
            if (lane >= o) inc *= v;
        }
        float excl = __shfl_up(inc, 1);
        if (lane == 0) excl = 1.f;
        T[c] = carry * excl;
        carry *= __shfl(inc, 63);
    }

    float w[3]; float accp = 0.f;
    #pragma unroll
    for (int c = 0; c < 3; c++) {
        float ww = alpha[c] * T[c];
        w[c] = (ww > FAST_THRES) ? ww : 0.f;
        accp += w[c];
    }
    #pragma unroll
    for (int o = 32; o > 0; o >>= 1) accp += __shfl_xor(accp, o);

    float outR = 1.f - accp, outG = 1.f - accp, outB = 1.f - accp;

    #pragma unroll
    for (int c = 0; c < 3; c++) {
        unsigned long long ball = __ballot(w[c] > 0.f);
        while (ball) {
            int src = __ffsll(ball) - 1;
            ball &= ball - 1;
            float sw  = __shfl(w[c], src);
            float scx = __shfl(cxa[c], src);
            float scy = __shfl(cya[c], src);
            float scz = __shfl(cza[c], src);
            float r0, r1, r2;
            wave_mlp(lane, scx, scy, scz, dx, dy, dz, equ,
                     dW0, db0, dW1, db1, dW2, db2,
                     cW0, cb0, cW1, cb1, cW2, cb2, r0, r1, r2);
            outR += sw * r0; outG += sw * r1; outB += sw * r2;
        }
    }

    if (lane < 3) {
        float val = (lane == 0) ? outR : ((lane == 1) ? outG : outB);
        out[r * 3 + lane] = val;
    }
}

extern "C" void kernel_launch(void* const* d_in, const int* in_sizes, int n_in,
                              void* d_out, int out_size, void* d_ws, size_t ws_size,
                              hipStream_t stream) {
    const float* rays_o = (const float*)d_in[0];
    const float* rays_d = (const float*)d_in[1];
    const float* dgrid  = (const float*)d_in[2];
    const float* equ    = (const float*)d_in[3];
    const float* dW0 = (const float*)d_in[4];
    const float* db0 = (const float*)d_in[5];
    const float* dW1 = (const float*)d_in[6];
    const float* db1 = (const float*)d_in[7];
    const float* dW2 = (const float*)d_in[8];
    const float* db2 = (const float*)d_in[9];
    const float* cW0 = (const float*)d_in[10];
    const float* cb0 = (const float*)d_in[11];
    const float* cW1 = (const float*)d_in[12];
    const float* cb1 = (const float*)d_in[13];
    const float* cW2 = (const float*)d_in[14];
    const float* cb2 = (const float*)d_in[15];
    float* out = (float*)d_out;

    float* blockmax = (float*)d_ws;   // KMAX_BLOCKS floats, written unconditionally

    k_max<<<KMAX_BLOCKS, 256, 0, stream>>>((const float4*)dgrid, blockmax);
    k_render<<<N_RAYS / 4, 256, 0, stream>>>(rays_o, rays_d, dgrid, equ,
                                             dW0, db0, dW1, db1, dW2, db2,
                                             cW0, cb0, cW1, cb1, cW2, cb2,
                                             blockmax, out);
}